// Round 7
// baseline (219.576 us; speedup 1.0000x reference)
//
#include <hip/hip_runtime.h>
#include <hip/hip_bf16.h>
#include <math.h>

#define Bv 8
#define Tv 32
#define Nv 500
#define Fin 64
#define Hv 128
#define Ev 8000
#define Kv 3
#define BT (Bv*Tv)      /* 256 */
#define ROWS (BT*Nv)    /* 128000 */
#define TP (Tv+2)       /* 34 LDS time rows (1 pad each side) */
#define KK (Kv*Hv)      /* 384: flattened conv K dim */
#define LDSROW 144      /* 288B row stride for hs */
#define NP 512          /* padded node count (K and M of the agg GEMM) */
#define NCOL (BT*Fin)   /* 16384 columns of X / AGG */

typedef __attribute__((ext_vector_type(8))) short s8v;   // 8 bf16 = 4 VGPRs
typedef __attribute__((ext_vector_type(4))) float f4v;   // MFMA acc

__device__ __forceinline__ short f2bs(float f){
    union { __hip_bfloat16 h; short s; } u;
    u.h = __float2bfloat16(f);
    return u.s;
}
// A&S 7.1.26 erf approx, |err| <= 1.5e-7 (exact-GELU tolerance is 0.103 here)
__device__ __forceinline__ float erf_fast(float x){
    float a = fabsf(x);
    float t = __builtin_amdgcn_rcpf(fmaf(0.3275911f, a, 1.0f));
    float p = t*fmaf(t, fmaf(t, fmaf(t, fmaf(t, 1.061405429f, -1.453152027f),
                     1.421413741f), -0.284496736f), 0.254829592f);
    float e = exp2f(-a*a*1.442695041f);
    return copysignf(1.0f - p*e, x);
}
__device__ __forceinline__ float gelu_exact(float v){
    return 0.5f*v*(1.0f + erf_fast(v*0.70710678118654752440f));
}

// ---- edge scatter: weighted degree + dense adjacency accumulate (fp32) ----
__global__ void k_prep1(const int* __restrict__ ei, const float* __restrict__ ew,
                        float* __restrict__ deg, float* __restrict__ Adense){
    int e = blockIdx.x*256 + threadIdx.x;
    if (e >= Ev) return;
    int s = ei[e], d = ei[Ev + e];
    float w = ew[e];
    atomicAdd(&deg[d], w);
    atomicAdd(&Adense[d*NP + s], w);
}

// ---- dinv (self-loop weight 1 included) ----
__global__ void k_prep2(const float* __restrict__ deg, float* __restrict__ dinv){
    int tid = threadIdx.x;
    if (tid < Nv) dinv[tid] = rsqrtf(deg[tid] + 1.0f);
}

// ---- normalize + self-loop + cast: Ab[d][s] = dinv[d]*dinv[s]*(A+I) bf16 ----
__global__ __launch_bounds__(256) void k_anorm(const float* __restrict__ Adense,
        const float* __restrict__ dinv, short* __restrict__ Ab){
    int idx = blockIdx.x*256 + threadIdx.x;   // NP*NP total
    int d = idx >> 9, s = idx & (NP-1);
    float v = Adense[idx] + ((d == s) ? 1.0f : 0.0f);
    float dd = (d < Nv) ? dinv[d] : 0.f;
    float ds = (s < Nv) ? dinv[s] : 0.f;
    Ab[idx] = f2bs(v * dd * ds);
}

// ---- x (bt,n,c) fp32 -> X2b[n][bt*64+c] bf16 AND X2bT[bt*64+c][n] bf16;
//      tail blocks convert weights ----
__global__ __launch_bounds__(256) void k_xpose(const float* __restrict__ x,
        short* __restrict__ X2b, short* __restrict__ X2bT,
        const float* __restrict__ W, const float* __restrict__ Wg,
        const float* __restrict__ Wr, short* __restrict__ W2,
        short* __restrict__ Wgt, short* __restrict__ Wrt){
    int bid = blockIdx.x;
    if (bid < 2048){
        __shared__ short ls[64*68];          // stride 68 shorts (136B, 8B-aligned)
        int bt = bid >> 3, nt = bid & 7;
        int n0 = nt*64;
        int rows = (n0 + 64 <= Nv) ? 64 : (Nv - n0);   // 64 or 52
        int tid = threadIdx.x;
        if (rows < 64){
            for (int j = tid; j < (64-rows)*68; j += 256) ls[rows*68 + j] = 0;
        }
        const float* xp = x + ((size_t)bt*Nv + n0)*64;
        for (int q = tid; q < rows*16; q += 256){
            int i = q >> 4, c4 = q & 15;
            float4 v = ((const float4*)xp)[q];
            short4 sv;
            sv.x = f2bs(v.x); sv.y = f2bs(v.y); sv.z = f2bs(v.z); sv.w = f2bs(v.w);
            *(short4*)&ls[i*68 + c4*4] = sv;
        }
        __syncthreads();
        // X2b rows: 16 chunks of 4 shorts per row (matches ls fill layout)
        for (int q = tid; q < 64*16; q += 256){
            int i = q >> 4, c4 = q & 15;
            if (i < rows)
                *(short4*)(X2b + (size_t)(n0+i)*NCOL + bt*64 + c4*4)
                    = *(const short4*)&ls[i*68 + c4*4];
        }
        // X2bT rows: row col=bt*64+c, cols n0..n0+63 (zero-padded past Nv)
        for (int q = tid; q < 64*8; q += 256){
            int c = q & 63, ch = q >> 6;
            s8v v;
            #pragma unroll
            for (int j = 0; j < 8; ++j) v[j] = ls[(ch*8 + j)*68 + c];
            *(s8v*)(X2bT + (size_t)(bt*64 + c)*NP + n0 + ch*8) = v;
        }
    } else {
        int idx = (bid - 2048)*256 + threadIdx.x;
        if (idx < Hv*Hv*Kv){
            int o = idx/(Hv*Kv);
            int rem = idx - o*(Hv*Kv);
            int i = rem/Kv, k = rem - i*Kv;
            W2[o*KK + k*Hv + i] = f2bs(W[idx]);           // W2[o][k*128+i]
        } else if (idx < Hv*Hv*Kv + Hv*64){
            int j = idx - Hv*Hv*Kv;
            int o = j >> 6, k = j & 63;
            Wgt[j] = f2bs(Wg[k*Hv + o]);                  // Wgt[o][k]
        } else if (idx < Hv*Hv*Kv + 2*Hv*64){
            int j = idx - Hv*Hv*Kv - Hv*64;
            int o = j >> 6, k = j & 63;
            Wrt[j] = f2bs(Wr[k*Hv + o]);                  // Wrt[o][k]
        }
    }
}

// ---- dense agg GEMM: AGG2[n][col] = sum_s Ab[n][s] * X2bT[col][s] ----
// block = 4 waves, tile M=64 x N=256, K=512; wave w owns cols [w*64,w*64+64).
__global__ __launch_bounds__(256) void k_aggemm(const short* __restrict__ Ab,
        const short* __restrict__ X2bT, short* __restrict__ AGG2){
    __shared__ short cs[64*264];     // repack tile (stride 264 shorts = 16B-aligned)
    int tid = threadIdx.x;
    int w = tid >> 6, lane = tid & 63, quad = lane >> 4, laneo = lane & 15;
    int m_base = (blockIdx.x >> 6) * 64;          // 8 m-blocks
    int c_base = (blockIdx.x & 63) * 256;         // 64 col-blocks
    f4v acc[4][4];
    #pragma unroll
    for (int mt = 0; mt < 4; ++mt)
        #pragma unroll
        for (int nt = 0; nt < 4; ++nt)
            acc[mt][nt] = (f4v){0.f,0.f,0.f,0.f};
    const short* ap0 = Ab + (size_t)(m_base + laneo)*NP + quad*8;
    const short* bp0 = X2bT + (size_t)(c_base + w*64 + laneo)*NP + quad*8;
    #pragma unroll 4
    for (int k0 = 0; k0 < NP; k0 += 32){
        s8v af[4], bf[4];
        #pragma unroll
        for (int mt = 0; mt < 4; ++mt) af[mt] = *(const s8v*)(ap0 + (size_t)mt*16*NP + k0);
        #pragma unroll
        for (int nt = 0; nt < 4; ++nt) bf[nt] = *(const s8v*)(bp0 + (size_t)nt*16*NP + k0);
        #pragma unroll
        for (int mt = 0; mt < 4; ++mt)
            #pragma unroll
            for (int nt = 0; nt < 4; ++nt)
                acc[mt][nt] = __builtin_amdgcn_mfma_f32_16x16x32_bf16(af[mt], bf[nt], acc[mt][nt], 0,0,0);
    }
    #pragma unroll
    for (int mt = 0; mt < 4; ++mt)
        #pragma unroll
        for (int nt = 0; nt < 4; ++nt)
            #pragma unroll
            for (int r = 0; r < 4; ++r){
                int row = mt*16 + quad*4 + r;          // C layout: row=quad*4+r
                int col = w*64 + nt*16 + laneo;        // col=laneo
                cs[row*264 + col] = f2bs(acc[mt][nt][r]);
            }
    __syncthreads();
    // 64 rows x 32 chunks of 8 shorts (s8v = 16B): full 256-short coverage
    for (int q = tid; q < 64*32; q += 256){
        int row = q >> 5, ch = q & 31;
        *(s8v*)(AGG2 + (size_t)(m_base + row)*NCOL + c_base + ch*8)
            = *(const s8v*)&cs[row*264 + ch*8];
    }
}

// ---- mega kernel: GCN GEMM (K=64) -> GELU -> LDS; residual GEMM (K=64);
//      temporal conv GEMM (K=384); bias+GELU+residual+LayerNorm -> out ----
// block = 4 waves, 2 nodes; wave w owns output channels [w*32, w*32+32).
__global__ __launch_bounds__(256, 2) void k_mega(
        const short* __restrict__ AGG2, const short* __restrict__ X2b,
        const short* __restrict__ W2, const short* __restrict__ Wgt,
        const short* __restrict__ Wrt,
        const float* __restrict__ bg, const float* __restrict__ btm,
        const float* __restrict__ br, const float* __restrict__ lw,
        const float* __restrict__ lb, float* __restrict__ out){
    __shared__ short hs[2*TP*LDSROW];      // 19584 B
    __shared__ float red[Tv][4][2];
    int tid  = threadIdx.x;
    int w    = tid >> 6;
    int lane = tid & 63;
    int quad = lane >> 4;
    int laneo = lane & 15;
    int bid = blockIdx.x;
    int b  = bid / 250;
    int n0 = (bid - b*250) * 2;
    int o_base = w*32;

    float bgv[2], bbv[2], brv[2], lwv[2], lbv[2];
    #pragma unroll
    for (int nt = 0; nt < 2; ++nt){
        int o = o_base + nt*16 + laneo;
        bgv[nt] = bg[o]; bbv[nt] = btm[o]; brv[nt] = br[o];
        lwv[nt] = lw[o]; lbv[nt] = lb[o];
    }

    // GCN B fragments (K=64: 2 k-steps)
    s8v bwg[2][2];
    #pragma unroll
    for (int nt = 0; nt < 2; ++nt){
        const short* wp = Wgt + (o_base + nt*16 + laneo)*64 + quad*8;
        bwg[nt][0] = *(const s8v*)wp;
        bwg[nt][1] = *(const s8v*)(wp + 32);
    }

    // zero the pad rows (tp=0, tp=33) of both nodes
    if (tid < 64){
        int node = tid >> 5, rem = tid & 31;
        int tp = (rem >> 4)*(TP-1), c8 = rem & 15;
        s8v z = {0,0,0,0,0,0,0,0};
        *(s8v*)&hs[node*(TP*LDSROW) + tp*LDSROW + c8*8] = z;
    }

    // ---- stage: GCN GEMM per node, GELU, write h to LDS (A-layout rows) ----
    for (int g = 0; g < 2; ++g){
        int n = n0 + g;
        const short* ap = AGG2 + ((size_t)n*BT + b*Tv)*64;
        #pragma unroll
        for (int m = 0; m < 2; ++m){
            const short* arp = ap + (m*16 + laneo)*64 + quad*8;
            s8v a0 = *(const s8v*)arp;
            s8v a1 = *(const s8v*)(arp + 32);
            f4v h0 = {0.f,0.f,0.f,0.f}, h1 = {0.f,0.f,0.f,0.f};
            h0 = __builtin_amdgcn_mfma_f32_16x16x32_bf16(a0, bwg[0][0], h0, 0,0,0);
            h0 = __builtin_amdgcn_mfma_f32_16x16x32_bf16(a1, bwg[0][1], h0, 0,0,0);
            h1 = __builtin_amdgcn_mfma_f32_16x16x32_bf16(a0, bwg[1][0], h1, 0,0,0);
            h1 = __builtin_amdgcn_mfma_f32_16x16x32_bf16(a1, bwg[1][1], h1, 0,0,0);
            #pragma unroll
            for (int r = 0; r < 4; ++r){
                int tp = m*16 + quad*4 + r + 1;     // C layout: row=quad*4+r
                short* hrow = &hs[g*(TP*LDSROW) + tp*LDSROW];
                hrow[o_base + laneo]      = f2bs(gelu_exact(h0[r] + bgv[0]));
                hrow[o_base + 16 + laneo] = f2bs(gelu_exact(h1[r] + bgv[1]));
            }
        }
    }

    // conv + residual B fragments
    s8v breg[2][12], bwr[2][2];
    #pragma unroll
    for (int nt = 0; nt < 2; ++nt){
        int o = o_base + nt*16 + laneo;
        const short* wp = W2 + o*KK + quad*8;
        #pragma unroll
        for (int s = 0; s < 12; ++s)
            breg[nt][s] = *(const s8v*)(wp + s*32);
        const short* wr = Wrt + o*64 + quad*8;
        bwr[nt][0] = *(const s8v*)wr;
        bwr[nt][1] = *(const s8v*)(wr + 32);
    }
    __syncthreads();

    for (int g = 0; g < 2; ++g){
        int n = n0 + g;
        // ---- temporal conv MFMA: 2 m-tiles x 12 K-steps x 2 n-tiles ----
        f4v acc[2][2];
        #pragma unroll
        for (int m = 0; m < 2; ++m)
            #pragma unroll
            for (int nt = 0; nt < 2; ++nt)
                acc[m][nt] = (f4v){0.f,0.f,0.f,0.f};
        #pragma unroll
        for (int m = 0; m < 2; ++m){
            #pragma unroll
            for (int s = 0; s < 12; ++s){
                int k  = s >> 2;
                int i0 = (s & 3) * 32;
                int tp = m*16 + laneo + k;
                s8v a = *(const s8v*)&hs[g*(TP*LDSROW) + tp*LDSROW + i0 + quad*8];
                acc[m][0] = __builtin_amdgcn_mfma_f32_16x16x32_bf16(a, breg[0][s], acc[m][0], 0,0,0);
                acc[m][1] = __builtin_amdgcn_mfma_f32_16x16x32_bf16(a, breg[1][s], acc[m][1], 0,0,0);
            }
        }
        // ---- residual GEMM from X2b window ----
        f4v racc[2][2];
        #pragma unroll
        for (int m = 0; m < 2; ++m)
            #pragma unroll
            for (int nt = 0; nt < 2; ++nt)
                racc[m][nt] = (f4v){0.f,0.f,0.f,0.f};
        const short* xp = X2b + ((size_t)n*BT + b*Tv)*64;
        #pragma unroll
        for (int m = 0; m < 2; ++m){
            const short* xrp = xp + (m*16 + laneo)*64 + quad*8;
            s8v a0 = *(const s8v*)xrp;
            s8v a1 = *(const s8v*)(xrp + 32);
            racc[m][0] = __builtin_amdgcn_mfma_f32_16x16x32_bf16(a0, bwr[0][0], racc[m][0], 0,0,0);
            racc[m][0] = __builtin_amdgcn_mfma_f32_16x16x32_bf16(a1, bwr[0][1], racc[m][0], 0,0,0);
            racc[m][1] = __builtin_amdgcn_mfma_f32_16x16x32_bf16(a0, bwr[1][0], racc[m][1], 0,0,0);
            racc[m][1] = __builtin_amdgcn_mfma_f32_16x16x32_bf16(a1, bwr[1][1], racc[m][1], 0,0,0);
        }
        // ---- epilogue: bias+GELU+residual, LN stats ----
        size_t obase = ((size_t)b*Tv*Nv + n)*Hv;
        float yv[2][2][4];
        float srow[2][4], ssrow[2][4];
        #pragma unroll
        for (int m = 0; m < 2; ++m)
            #pragma unroll
            for (int r = 0; r < 4; ++r){ srow[m][r] = 0.f; ssrow[m][r] = 0.f; }
        #pragma unroll
        for (int m = 0; m < 2; ++m){
            #pragma unroll
            for (int nt = 0; nt < 2; ++nt){
                #pragma unroll
                for (int r = 0; r < 4; ++r){
                    float gv = gelu_exact(acc[m][nt][r] + bbv[nt]);
                    float y = gv + racc[m][nt][r] + brv[nt];
                    yv[m][nt][r] = y;
                    srow[m][r] += y; ssrow[m][r] += y*y;
                }
            }
        }
        #pragma unroll
        for (int m = 0; m < 2; ++m)
            #pragma unroll
            for (int r = 0; r < 4; ++r){
                #pragma unroll
                for (int msk = 8; msk >= 1; msk >>= 1){
                    srow[m][r]  += __shfl_xor(srow[m][r],  msk, 64);
                    ssrow[m][r] += __shfl_xor(ssrow[m][r], msk, 64);
                }
            }
        if (laneo == 0){
            #pragma unroll
            for (int m = 0; m < 2; ++m)
                #pragma unroll
                for (int r = 0; r < 4; ++r){
                    int t = m*16 + quad*4 + r;
                    red[t][w][0] = srow[m][r];
                    red[t][w][1] = ssrow[m][r];
                }
        }
        __syncthreads();
        #pragma unroll
        for (int m = 0; m < 2; ++m){
            #pragma unroll
            for (int r = 0; r < 4; ++r){
                int t = m*16 + quad*4 + r;
                float s  = red[t][0][0] + red[t][1][0] + red[t][2][0] + red[t][3][0];
                float ss = red[t][0][1] + red[t][1][1] + red[t][2][1] + red[t][3][1];
                float mu = s * (1.f/128.f);
                float var = fmaxf(ss * (1.f/128.f) - mu*mu, 0.f);
                float rstd = rsqrtf(var + 1e-5f);
                #pragma unroll
                for (int nt = 0; nt < 2; ++nt){
                    int o = o_base + nt*16 + laneo;
                    out[obase + (size_t)t*Nv*Hv + o] =
                        (yv[m][nt][r] - mu)*rstd*lwv[nt] + lbv[nt];
                }
            }
        }
        __syncthreads();
    }
}

extern "C" void kernel_launch(void* const* d_in, const int* in_sizes, int n_in,
                              void* d_out, int out_size, void* d_ws, size_t ws_size,
                              hipStream_t stream){
    const float* x   = (const float*)d_in[0];
    const int*   ei  = (const int*)d_in[1];
    const float* ew  = (const float*)d_in[2];
    const float* Wg  = (const float*)d_in[3];
    const float* bg  = (const float*)d_in[4];
    const float* Wtm = (const float*)d_in[5];
    const float* btm = (const float*)d_in[6];
    const float* lw  = (const float*)d_in[7];
    const float* lb  = (const float*)d_in[8];
    const float* Wr  = (const float*)d_in[9];
    const float* br  = (const float*)d_in[10];
    float* out = (float*)d_out;

    char* ws = (char*)d_ws;
    float* Adense = (float*)(ws + 0);            // 1 MB (512*512*4)
    float* deg    = (float*)(ws + 1048576);      // 2048 B
    float* dinv   = (float*)(ws + 1050624);      // 2048 B
    short* Ab     = (short*)(ws + 1052672);      // 512 KB
    short* W2     = (short*)(ws + 1576960);      // 96 KB
    short* Wgt    = (short*)(ws + 1675264);      // 16 KB
    short* Wrt    = (short*)(ws + 1691648);      // 16 KB
    short* X2b    = (short*)(ws + 1708032);      // 16.78 MB
    short* X2bT   = (short*)(ws + 18485248);     // 16.78 MB
    short* AGG2   = (short*)(ws + 35262464);     // 16.78 MB  (end ~52 MB)

    hipMemsetAsync(ws, 0, 1048576 + 2048, stream);   // Adense + deg

    k_prep1 <<<(Ev+255)/256, 256, 0, stream>>>(ei, ew, deg, Adense);
    k_prep2 <<<1, 512, 0, stream>>>(deg, dinv);
    k_anorm <<<(NP*NP)/256, 256, 0, stream>>>(Adense, dinv, Ab);
    k_xpose <<<2048 + 256, 256, 0, stream>>>(x, X2b, X2bT, Wtm, Wg, Wr, W2, Wgt, Wrt);
    k_aggemm<<<8*64, 256, 0, stream>>>(Ab, X2bT, AGG2);
    k_mega  <<<2000, 256, 0, stream>>>(AGG2, X2b, W2, Wgt, Wrt,
                                       bg, btm, br, lw, lb, out);
}